// Round 6
// baseline (354.278 us; speedup 1.0000x reference)
//
#include <hip/hip_runtime.h>

typedef __attribute__((ext_vector_type(8))) short short8;
typedef __attribute__((ext_vector_type(4))) float f32x4;

// ---- problem constants ----
#define NSPAN 1024
#define DDIM  512
#define HDIM  150
#define HPAD  160
#define WINW  250
#define OUTW  251

// ---- LDS layout (pair_main), bytes ----
// A2 (h1 bf16 [128] rows x 320B, wave-private rows) @0 (40960)
// sL (f32[128]) @40960 (512)
#define SL_OFF  40960
#define SMEM_BYTES 41472

__device__ __forceinline__ unsigned short f2bf(float x) {
  union { float f; unsigned int u; } v; v.f = x;
  return (unsigned short)((v.u + 0x7fffu + ((v.u >> 16) & 1u)) >> 16);
}

// v_cvt_pk_bf16_f32: dst = {lo16=bf16(a), hi16=bf16(b)}, RNE
__device__ __forceinline__ unsigned int cvtpk(float a, float b) {
  unsigned int r;
  asm("v_cvt_pk_bf16_f32 %0, %1, %2" : "=v"(r) : "v"(a), "v"(b));
  return r;
}

// ---------------- merged prep (one launch; gemm part + misc part overlap) ----------------
// blocks [0,1024): pre1 = g@W1a + b1, gjb = g@W1b (fp32, exact; 2 rows per block)
// blocks [1024,1585): transpose + bf16 convert W1c -> w1cT[n][d], W2 -> w2T[n][k]; pad W3
__global__ __launch_bounds__(192) void prep_all(
    const float* __restrict__ g, const float* __restrict__ W1,
    const float* __restrict__ b1, const float* __restrict__ W2,
    const float* __restrict__ W3,
    float* __restrict__ pre1, float* __restrict__ gjb,
    unsigned short* __restrict__ w1cT, unsigned short* __restrict__ w2T,
    float* __restrict__ w3p)
{
  const int bx = blockIdx.x;
  if (bx < 1024) {
    __shared__ __align__(16) float gs[2 * DDIM];
    const int grp = bx >> 1;
    const int which = bx & 1;
    const int i0 = grp << 1;
    for (int idx = threadIdx.x; idx < (2 * DDIM / 4); idx += 192)
      ((float4*)gs)[idx] = ((const float4*)(g + (size_t)i0 * DDIM))[idx];
    __syncthreads();
    const int n = threadIdx.x;
    float a0 = 0.f, a1 = 0.f;
    if (n < HDIM) {
      const float* Wp = W1 + (size_t)which * DDIM * HDIM + n;
#pragma unroll 8
      for (int d = 0; d < DDIM; ++d) {
        float w = Wp[(size_t)d * HDIM];
        a0 += gs[d] * w;
        a1 += gs[DDIM + d] * w;
      }
    }
    if (n < HPAD) {
      float* dst = which ? gjb : pre1;
      float add = (which == 0 && n < HDIM) ? b1[n] : 0.f;
      dst[(size_t)i0 * HPAD + n]       = (n < HDIM) ? (a0 + add) : 0.f;
      dst[(size_t)(i0 + 1) * HPAD + n] = (n < HDIM) ? (a1 + add) : 0.f;
    }
  } else {
    int id = (bx - 1024) * 192 + threadIdx.x;
    if (id < HPAD * DDIM) {                       // 81920: id = d*160 + n
      int d = id / HPAD, n = id % HPAD;
      float v = (n < HDIM) ? W1[(size_t)(2 * DDIM + d) * HDIM + n] : 0.f;
      w1cT[(size_t)n * DDIM + d] = f2bf(v);
    } else if (id < HPAD * DDIM + HPAD * HPAD) {  // +25600: id2 = k*160 + n
      int id2 = id - HPAD * DDIM;
      int k = id2 / HPAD, n = id2 % HPAD;
      float v = (n < HDIM && k < HDIM) ? W2[(size_t)k * HDIM + n] : 0.f;
      w2T[(size_t)n * HPAD + k] = f2bf(v);
    } else if (id < HPAD * DDIM + HPAD * HPAD + HPAD) {
      int n = id - HPAD * DDIM - HPAD * HPAD;
      w3p[n] = (n < HDIM) ? W3[n] : 0.f;
    }
  }
}

// ---------------- main fused kernel ----------------
// block = (i, half): 128 window rows. 4 waves, each owns rows [wv*32, wv*32+32).
// GEMM1/GEMM2: B fragments read DIRECTLY from L2 (w1cT / w2T), A built in registers
// from global g. No LDS staging, no K-loop barriers: waves stream independently
// and TLP (12 waves/CU) hides L2 latency. Single barrier = sL publish.
__global__ __launch_bounds__(256, 3) void pair_main(
    const float* __restrict__ g, const float* __restrict__ sm,
    const float* __restrict__ pre1, const float* __restrict__ gjb,
    const unsigned short* __restrict__ w1cT, const unsigned short* __restrict__ w2T,
    const float* __restrict__ w3p, const float* __restrict__ b2,
    const float* __restrict__ b3, float* __restrict__ out)
{
  __shared__ __align__(16) char smem[SMEM_BYTES];
  const int tid = threadIdx.x;
  const int lane = tid & 63;
  const int wv = tid >> 6;
  const int l15 = lane & 15;
  const int lq = lane >> 4;          // 0..3
  const int i = blockIdx.x >> 1;
  const int mbase = (blockIdx.x & 1) << 7;

  // per-lane A row pointers (mt = 0,1): row = mbase + wv*32 + mt*16 + l15
  const int row0 = mbase + (wv << 5) + l15;
  int j0 = i - WINW + row0;
  j0 = j0 < 0 ? 0 : (j0 > NSPAN - 1 ? NSPAN - 1 : j0);
  int j1 = i - WINW + row0 + 16;
  j1 = j1 < 0 ? 0 : (j1 > NSPAN - 1 ? NSPAN - 1 : j1);
  const float* gjr0 = g + (size_t)j0 * DDIM + (lq << 3);
  const float* gjr1 = g + (size_t)j1 * DDIM + (lq << 3);
  const float* giR  = g + (size_t)i * DDIM + (lq << 3);

  // per-lane B base: fragment (nt, s) at bB + nt*16*DDIM + s*32 (elements)
  const unsigned short* bB = w1cT + (size_t)l15 * DDIM + (lq << 3);

  f32x4 acc[2][10];
#pragma unroll
  for (int mt = 0; mt < 2; ++mt)
#pragma unroll
    for (int nt = 0; nt < 10; ++nt)
      acc[mt][nt] = (f32x4){0.f, 0.f, 0.f, 0.f};

  // ---- GEMM1: [128 x 512] (g_i*g_j bf16, regs) @ [512 x 160] (W1c from L2) ----
#pragma unroll 2
  for (int s = 0; s < 16; ++s) {
    const int kf = s << 5;
    float4 x0 = *(const float4*)(gjr0 + kf), x1 = *(const float4*)(gjr0 + kf + 4);
    float4 y0 = *(const float4*)(gjr1 + kf), y1 = *(const float4*)(gjr1 + kf + 4);
    float4 g0 = *(const float4*)(giR + kf),  g1 = *(const float4*)(giR + kf + 4);
    uint4 aC0, aC1;
    aC0.x = cvtpk(x0.x * g0.x, x0.y * g0.y);
    aC0.y = cvtpk(x0.z * g0.z, x0.w * g0.w);
    aC0.z = cvtpk(x1.x * g1.x, x1.y * g1.y);
    aC0.w = cvtpk(x1.z * g1.z, x1.w * g1.w);
    aC1.x = cvtpk(y0.x * g0.x, y0.y * g0.y);
    aC1.y = cvtpk(y0.z * g0.z, y0.w * g0.w);
    aC1.z = cvtpk(y1.x * g1.x, y1.y * g1.y);
    aC1.w = cvtpk(y1.z * g1.z, y1.w * g1.w);
    short8 a0 = *(short8*)&aC0;
    short8 a1 = *(short8*)&aC1;
#pragma unroll
    for (int nt = 0; nt < 10; ++nt) {
      short8 bb = *(const short8*)(bB + nt * 16 * DDIM + kf);
      acc[0][nt] = __builtin_amdgcn_mfma_f32_16x16x32_bf16(a0, bb, acc[0][nt], 0, 0, 0);
      acc[1][nt] = __builtin_amdgcn_mfma_f32_16x16x32_bf16(a1, bb, acc[1][nt], 0, 0, 0);
    }
  }

  // ---- epilogue 1: h1 = relu(acc + pre1_i + gjb_j) -> A2 @0 (bf16, swizzled) ----
  // A2 rows are wave-private -> no barrier needed before GEMM2.
  float p1v[10];
#pragma unroll
  for (int nt = 0; nt < 10; ++nt)
    p1v[nt] = pre1[(size_t)i * HPAD + (nt << 4) + l15];

#pragma unroll
  for (int mt = 0; mt < 2; ++mt) {
#pragma unroll
    for (int rr = 0; rr < 4; ++rr) {
      const int row = (wv << 5) + (mt << 4) + (lq << 2) + rr;
      int j = i - WINW + mbase + row;
      j = j < 0 ? 0 : (j > NSPAN - 1 ? NSPAN - 1 : j);
      const float* gjr = gjb + (size_t)j * HPAD;
      const int sw = ((row + (row >> 2)) & 3) << 4;
      const int rb = row * 320;
#pragma unroll
      for (int np = 0; np < 5; ++np) {
        const int n0 = np << 1, n1 = n0 + 1;
        float v0 = fmaxf(acc[mt][n0][rr] + p1v[n0] + gjr[(n0 << 4) + l15], 0.f);
        float v1 = fmaxf(acc[mt][n1][rr] + p1v[n1] + gjr[(n1 << 4) + l15], 0.f);
        unsigned int u = cvtpk(v0, v1);
        *(unsigned short*)(smem + ((rb + (((n0 << 4) + l15) << 1)) ^ sw)) = (unsigned short)u;
        *(unsigned short*)(smem + ((rb + (((n1 << 4) + l15) << 1)) ^ sw)) = (unsigned short)(u >> 16);
      }
    }
  }

  // ---- GEMM2: [128 x 160] (h1 from LDS, own rows) @ [160 x 160] (W2 from L2) ----
  // reuse acc[][] as the GEMM2 accumulator (lifetimes disjoint)
  int ya[2];
#pragma unroll
  for (int mt = 0; mt < 2; ++mt) {
    int row = (wv << 5) + (mt << 4) + l15;
    ya[mt] = ((row * 320) + (lq << 4)) ^ (((row + (row >> 2)) & 3) << 4);
  }

#pragma unroll
  for (int mt = 0; mt < 2; ++mt)
#pragma unroll
    for (int nt = 0; nt < 10; ++nt)
      acc[mt][nt] = (f32x4){0.f, 0.f, 0.f, 0.f};

#pragma unroll
  for (int c = 0; c < 5; ++c) {
    short8 a0 = *(const short8*)(smem + ya[0] + (c << 6));
    short8 a1 = *(const short8*)(smem + ya[1] + (c << 6));
#pragma unroll
    for (int nt = 0; nt < 10; ++nt) {
      short8 bb = *(const short8*)(w2T + (size_t)((nt << 4) + l15) * HPAD + (c << 5) + (lq << 3));
      acc[0][nt] = __builtin_amdgcn_mfma_f32_16x16x32_bf16(a0, bb, acc[0][nt], 0, 0, 0);
      acc[1][nt] = __builtin_amdgcn_mfma_f32_16x16x32_bf16(a1, bb, acc[1][nt], 0, 0, 0);
    }
  }

  // ---- GEMM3: s = relu(acc + b2) @ W3, 16-lane shuffle reduce ----
  float w3v[10], b2v[10];
#pragma unroll
  for (int nt = 0; nt < 10; ++nt) {
    int nn = (nt << 4) + l15;
    w3v[nt] = w3p[nn];
    b2v[nt] = (nn < HDIM) ? b2[nn] : 0.f;
  }
  float* sL = (float*)(smem + SL_OFF);
#pragma unroll
  for (int mt = 0; mt < 2; ++mt) {
#pragma unroll
    for (int rr = 0; rr < 4; ++rr) {
      float part = 0.f;
#pragma unroll
      for (int nt = 0; nt < 10; ++nt) {
        float h2 = fmaxf(acc[mt][nt][rr] + b2v[nt], 0.f);
        part = fmaf(h2, w3v[nt], part);
      }
      part += __shfl_xor(part, 1);
      part += __shfl_xor(part, 2);
      part += __shfl_xor(part, 4);
      part += __shfl_xor(part, 8);
      if (l15 == 0)
        sL[(wv << 5) + (mt << 4) + (lq << 2) + rr] = part;
    }
  }
  __syncthreads();

  // ---- final: sij = sm_i + sm_j + s + b3, masked; epsilon col = 0 ----
  if (tid < 128) {
    const int rg = mbase + tid;
    if (rg <= WINW) {
      const int j = i - WINW + rg;
      float v = 0.f;
      if (rg < WINW && j >= 0)
        v = sL[tid] + b3[0] + sm[i] + sm[j];
      out[(size_t)i * OUTW + rg] = v;
    }
  }
}

extern "C" void kernel_launch(void* const* d_in, const int* in_sizes, int n_in,
                              void* d_out, int out_size, void* d_ws, size_t ws_size,
                              hipStream_t stream) {
  const float* g  = (const float*)d_in[0];
  const float* sm = (const float*)d_in[1];
  const float* W1 = (const float*)d_in[2];
  const float* b1 = (const float*)d_in[3];
  const float* W2 = (const float*)d_in[4];
  const float* b2 = (const float*)d_in[5];
  const float* W3 = (const float*)d_in[6];
  const float* b3 = (const float*)d_in[7];
  float* out = (float*)d_out;

  // workspace carve (total 1,526,400 B)
  char* ws = (char*)d_ws;
  float* pre1          = (float*)ws;                         // 1024*160*4 = 655360
  float* gjb           = (float*)(ws + 655360);              // 655360
  unsigned short* w1cT = (unsigned short*)(ws + 1310720);    // 160*512*2 = 163840
  unsigned short* w2T  = (unsigned short*)(ws + 1474560);    // 160*160*2 = 51200
  float* w3p           = (float*)(ws + 1525760);             // 640

  // merged prep: blocks [0,1024) gemm part, [1024,1585) misc part
  prep_all<<<1585, 192, 0, stream>>>(g, W1, b1, W2, W3, pre1, gjb, w1cT, w2T, w3p);
  pair_main<<<2048, 256, 0, stream>>>(g, sm, pre1, gjb, w1cT, w2T, w3p, b2, b3, out);
}

// Round 7
// 253.944 us; speedup vs baseline: 1.3951x; 1.3951x over previous
//
#include <hip/hip_runtime.h>

typedef __attribute__((ext_vector_type(8))) short short8;
typedef __attribute__((ext_vector_type(4))) float f32x4;

// ---- problem constants ----
#define NSPAN 1024
#define DDIM  512
#define HDIM  150
#define HPAD  160
#define WINW  250
#define OUTW  251

// ---- LDS layout (pair_main), bytes ----
// GEMM1: B tri-buffer @0 / @10240 / @20480 (each 160 rows x 64B)  -> 30720
// GEMM2: A2 (h1 bf16 [128] rows x 320B, wave-private rows) @0..40960 (aliases B bufs)
// GEMM3: sL (f32[128]) @40960
#define SL_OFF  40960
#define SMEM_BYTES 41472

__device__ __forceinline__ unsigned short f2bf(float x) {
  union { float f; unsigned int u; } v; v.f = x;
  return (unsigned short)((v.u + 0x7fffu + ((v.u >> 16) & 1u)) >> 16);
}

// v_cvt_pk_bf16_f32: dst = {lo16=bf16(a), hi16=bf16(b)}, RNE
__device__ __forceinline__ unsigned int cvtpk(float a, float b) {
  unsigned int r;
  asm("v_cvt_pk_bf16_f32 %0, %1, %2" : "=v"(r) : "v"(a), "v"(b));
  return r;
}

__device__ __forceinline__ void gload_lds16(const void* g, void* l) {
  __builtin_amdgcn_global_load_lds(
      (const __attribute__((address_space(1))) unsigned int*)g,
      (__attribute__((address_space(3))) unsigned int*)l, 16, 0, 0);
}

// ---------------- merged prep (one launch; gemm part + misc part overlap) ----------------
__global__ __launch_bounds__(192) void prep_all(
    const float* __restrict__ g, const float* __restrict__ W1,
    const float* __restrict__ b1, const float* __restrict__ W2,
    const float* __restrict__ W3,
    float* __restrict__ pre1, float* __restrict__ gjb,
    unsigned short* __restrict__ w1cT, unsigned short* __restrict__ w2T,
    float* __restrict__ w3p)
{
  const int bx = blockIdx.x;
  if (bx < 1024) {
    __shared__ __align__(16) float gs[2 * DDIM];
    const int grp = bx >> 1;
    const int which = bx & 1;
    const int i0 = grp << 1;
    for (int idx = threadIdx.x; idx < (2 * DDIM / 4); idx += 192)
      ((float4*)gs)[idx] = ((const float4*)(g + (size_t)i0 * DDIM))[idx];
    __syncthreads();
    const int n = threadIdx.x;
    float a0 = 0.f, a1 = 0.f;
    if (n < HDIM) {
      const float* Wp = W1 + (size_t)which * DDIM * HDIM + n;
#pragma unroll 8
      for (int d = 0; d < DDIM; ++d) {
        float w = Wp[(size_t)d * HDIM];
        a0 += gs[d] * w;
        a1 += gs[DDIM + d] * w;
      }
    }
    if (n < HPAD) {
      float* dst = which ? gjb : pre1;
      float add = (which == 0 && n < HDIM) ? b1[n] : 0.f;
      dst[(size_t)i0 * HPAD + n]       = (n < HDIM) ? (a0 + add) : 0.f;
      dst[(size_t)(i0 + 1) * HPAD + n] = (n < HDIM) ? (a1 + add) : 0.f;
    }
  } else {
    int id = (bx - 1024) * 192 + threadIdx.x;
    if (id < HPAD * DDIM) {                       // 81920: id = d*160 + n
      int d = id / HPAD, n = id % HPAD;
      float v = (n < HDIM) ? W1[(size_t)(2 * DDIM + d) * HDIM + n] : 0.f;
      w1cT[(size_t)n * DDIM + d] = f2bf(v);
    } else if (id < HPAD * DDIM + HPAD * HPAD) {  // +25600: id2 = k*160 + n
      int id2 = id - HPAD * DDIM;
      int k = id2 / HPAD, n = id2 % HPAD;
      float v = (n < HDIM && k < HDIM) ? W2[(size_t)k * HDIM + n] : 0.f;
      w2T[(size_t)n * HPAD + k] = f2bf(v);
    } else if (id < HPAD * DDIM + HPAD * HPAD + HPAD) {
      int n = id - HPAD * DDIM - HPAD * HPAD;
      w3p[n] = (n < HDIM) ? W3[n] : 0.f;
    }
  }
}

// ---------------- main fused kernel ----------------
// block = (i, half): 128 window rows. 4 waves, each owns rows [wv*32, wv*32+32).
// GEMM1: B staged via global_load_lds into a 3-deep LDS ring with COUNTED vmcnt
// (never vmcnt(0) in the loop) + raw s_barrier -> DMA(s+1) stays in flight across
// the barrier that releases step s. A-fragments built in registers from global g.
__global__ __launch_bounds__(256, 3) void pair_main(
    const float* __restrict__ g, const float* __restrict__ sm,
    const float* __restrict__ pre1, const float* __restrict__ gjb,
    const unsigned short* __restrict__ w1cT, const unsigned short* __restrict__ w2T,
    const float* __restrict__ w3p, const float* __restrict__ b2,
    const float* __restrict__ b3, float* __restrict__ out)
{
  __shared__ __align__(16) char smem[SMEM_BYTES];
  const int tid = threadIdx.x;
  const int lane = tid & 63;
  const int wv = tid >> 6;
  const int l15 = lane & 15;
  const int lq = lane >> 4;          // 0..3
  const int i = blockIdx.x >> 1;
  const int mbase = (blockIdx.x & 1) << 7;

  // per-lane A row pointers (mt = 0,1): row = mbase + wv*32 + mt*16 + l15
  const int row0 = mbase + (wv << 5) + l15;
  int j0 = i - WINW + row0;
  j0 = j0 < 0 ? 0 : (j0 > NSPAN - 1 ? NSPAN - 1 : j0);
  int j1 = i - WINW + row0 + 16;
  j1 = j1 < 0 ? 0 : (j1 > NSPAN - 1 ? NSPAN - 1 : j1);
  const float* gjr0 = g + (size_t)j0 * DDIM + (lq << 3);
  const float* gjr1 = g + (size_t)j1 * DDIM + (lq << 3);
  const float* giR  = g + (size_t)i * DDIM + (lq << 3);

  // B global_load_lds: per-lane inverse-swizzled source byte offsets (k0=0)
  unsigned int bsrc[3];
#pragma unroll
  for (int t = 0; t < 3; ++t) {
    int b = wv * 2560 + (t << 10) + (lane << 4);
    int m = b >> 7;                       // 128B row-pair block
    int bp = b ^ ((m & 7) << 4);          // involution within block
    int n = bp >> 6, o = bp & 63;
    bsrc[t] = (unsigned int)(n * 1024 + o);   // + s*64 at use (w1cT row = 1024B)
  }

  // B fragment read addresses (64B-stride rows, pair-XOR swizzle)
  int xb[10];
#pragma unroll
  for (int nt = 0; nt < 10; ++nt) {
    int nr = (nt << 4) + l15;
    xb[nt] = ((nr << 6) + (lq << 4)) ^ (((nr >> 1) & 7) << 4);
  }

  f32x4 acc[2][10];
#pragma unroll
  for (int mt = 0; mt < 2; ++mt)
#pragma unroll
    for (int nt = 0; nt < 10; ++nt)
      acc[mt][nt] = (f32x4){0.f, 0.f, 0.f, 0.f};

  const char* w1cB = (const char*)w1cT;

#define STAGE_B(sidx)                                                       \
  {                                                                         \
    char* ldsw = smem + ((sidx) % 3) * 10240 + wv * 2560;                   \
    const int kn_ = (sidx) << 6;                                            \
    gload_lds16(w1cB + bsrc[0] + kn_, ldsw);                                \
    gload_lds16(w1cB + bsrc[1] + kn_, ldsw + 1024);                         \
    if (lane < 32) gload_lds16(w1cB + bsrc[2] + kn_, ldsw + 2048);          \
  }

  // ---- prologue: A(0) loads, DMA(0), pack A(0) (DMA(0) stays in flight) ----
  uint4 aC0, aC1;
  {
    float4 x0 = *(const float4*)gjr0, x1 = *(const float4*)(gjr0 + 4);
    float4 y0 = *(const float4*)gjr1, y1 = *(const float4*)(gjr1 + 4);
    float4 g0 = *(const float4*)giR,  g1 = *(const float4*)(giR + 4);
    STAGE_B(0);
    aC0.x = cvtpk(x0.x * g0.x, x0.y * g0.y);
    aC0.y = cvtpk(x0.z * g0.z, x0.w * g0.w);
    aC0.z = cvtpk(x1.x * g1.x, x1.y * g1.y);
    aC0.w = cvtpk(x1.z * g1.z, x1.w * g1.w);
    aC1.x = cvtpk(y0.x * g0.x, y0.y * g0.y);
    aC1.y = cvtpk(y0.z * g0.z, y0.w * g0.w);
    aC1.z = cvtpk(y1.x * g1.x, y1.y * g1.y);
    aC1.w = cvtpk(y1.z * g1.z, y1.w * g1.w);
  }

  // ---- GEMM1: [128 x 512] (g_i*g_j bf16, regs) @ [512 x 160] (W1c via LDS ring) ----
  // per iter s: issue A(s+1) loads + DMA(s+1), vmcnt(9) retires DMA(s) (order-robust:
  // waits "all but the 9 newest"), s_barrier (NO drain), 20 MFMAs, pack A(s+1).
  // Ring depth 3 makes write(s+1) vs read(s-2) barrier-separated.
#pragma unroll
  for (int s = 0; s < 16; ++s) {
    float4 x0, x1, y0, y1, g0, g1;
    if (s < 15) {
      const int kf = (s + 1) << 5;
      x0 = *(const float4*)(gjr0 + kf); x1 = *(const float4*)(gjr0 + kf + 4);
      y0 = *(const float4*)(gjr1 + kf); y1 = *(const float4*)(gjr1 + kf + 4);
      g0 = *(const float4*)(giR + kf);  g1 = *(const float4*)(giR + kf + 4);
      STAGE_B(s + 1);
      asm volatile("s_waitcnt vmcnt(9)" ::: "memory");
    } else {
      asm volatile("s_waitcnt vmcnt(0)" ::: "memory");
    }
    __builtin_amdgcn_s_barrier();

    const char* bcur = smem + (s % 3) * 10240;
    short8 a0 = *(short8*)&aC0;
    short8 a1 = *(short8*)&aC1;
#pragma unroll
    for (int nt = 0; nt < 10; ++nt) {
      short8 bb = *(const short8*)(bcur + xb[nt]);
      acc[0][nt] = __builtin_amdgcn_mfma_f32_16x16x32_bf16(a0, bb, acc[0][nt], 0, 0, 0);
      acc[1][nt] = __builtin_amdgcn_mfma_f32_16x16x32_bf16(a1, bb, acc[1][nt], 0, 0, 0);
    }
    if (s < 15) {
      aC0.x = cvtpk(x0.x * g0.x, x0.y * g0.y);
      aC0.y = cvtpk(x0.z * g0.z, x0.w * g0.w);
      aC0.z = cvtpk(x1.x * g1.x, x1.y * g1.y);
      aC0.w = cvtpk(x1.z * g1.z, x1.w * g1.w);
      aC1.x = cvtpk(y0.x * g0.x, y0.y * g0.y);
      aC1.y = cvtpk(y0.z * g0.z, y0.w * g0.w);
      aC1.z = cvtpk(y1.x * g1.x, y1.y * g1.y);
      aC1.w = cvtpk(y1.z * g1.z, y1.w * g1.w);
    }
  }
#undef STAGE_B
  __syncthreads();   // all waves done reading B ring before A2 overwrites [0,40960)

  // ---- epilogue 1: h1 = relu(acc + pre1_i + gjb_j) -> A2 @0 (bf16, swizzled) ----
  // A2 rows are wave-private -> no barrier needed before GEMM2.
  float p1v[10];
#pragma unroll
  for (int nt = 0; nt < 10; ++nt)
    p1v[nt] = pre1[(size_t)i * HPAD + (nt << 4) + l15];

#pragma unroll
  for (int mt = 0; mt < 2; ++mt) {
#pragma unroll
    for (int rr = 0; rr < 4; ++rr) {
      const int row = (wv << 5) + (mt << 4) + (lq << 2) + rr;
      int j = i - WINW + mbase + row;
      j = j < 0 ? 0 : (j > NSPAN - 1 ? NSPAN - 1 : j);
      const float* gjr = gjb + (size_t)j * HPAD;
      const int sw = ((row + (row >> 2)) & 3) << 4;
      const int rb = row * 320;
#pragma unroll
      for (int np = 0; np < 5; ++np) {
        const int n0 = np << 1, n1 = n0 + 1;
        float v0 = fmaxf(acc[mt][n0][rr] + p1v[n0] + gjr[(n0 << 4) + l15], 0.f);
        float v1 = fmaxf(acc[mt][n1][rr] + p1v[n1] + gjr[(n1 << 4) + l15], 0.f);
        unsigned int u = cvtpk(v0, v1);
        *(unsigned short*)(smem + ((rb + (((n0 << 4) + l15) << 1)) ^ sw)) = (unsigned short)u;
        *(unsigned short*)(smem + ((rb + (((n1 << 4) + l15) << 1)) ^ sw)) = (unsigned short)(u >> 16);
      }
    }
  }

  // ---- GEMM2: [128 x 160] (h1 from LDS, own rows) @ [160 x 160] (W2 from L2) ----
  int ya[2];
#pragma unroll
  for (int mt = 0; mt < 2; ++mt) {
    int row = (wv << 5) + (mt << 4) + l15;
    ya[mt] = ((row * 320) + (lq << 4)) ^ (((row + (row >> 2)) & 3) << 4);
  }

#pragma unroll
  for (int mt = 0; mt < 2; ++mt)
#pragma unroll
    for (int nt = 0; nt < 10; ++nt)
      acc[mt][nt] = (f32x4){0.f, 0.f, 0.f, 0.f};

#pragma unroll
  for (int c = 0; c < 5; ++c) {
    short8 a0 = *(const short8*)(smem + ya[0] + (c << 6));
    short8 a1 = *(const short8*)(smem + ya[1] + (c << 6));
#pragma unroll
    for (int nt = 0; nt < 10; ++nt) {
      short8 bb = *(const short8*)(w2T + (size_t)((nt << 4) + l15) * HPAD + (c << 5) + (lq << 3));
      acc[0][nt] = __builtin_amdgcn_mfma_f32_16x16x32_bf16(a0, bb, acc[0][nt], 0, 0, 0);
      acc[1][nt] = __builtin_amdgcn_mfma_f32_16x16x32_bf16(a1, bb, acc[1][nt], 0, 0, 0);
    }
  }

  // ---- GEMM3: s = relu(acc + b2) @ W3, 16-lane shuffle reduce ----
  float w3v[10], b2v[10];
#pragma unroll
  for (int nt = 0; nt < 10; ++nt) {
    int nn = (nt << 4) + l15;
    w3v[nt] = w3p[nn];
    b2v[nt] = (nn < HDIM) ? b2[nn] : 0.f;
  }
  float* sL = (float*)(smem + SL_OFF);
#pragma unroll
  for (int mt = 0; mt < 2; ++mt) {
#pragma unroll
    for (int rr = 0; rr < 4; ++rr) {
      float part = 0.f;
#pragma unroll
      for (int nt = 0; nt < 10; ++nt) {
        float h2 = fmaxf(acc[mt][nt][rr] + b2v[nt], 0.f);
        part = fmaf(h2, w3v[nt], part);
      }
      part += __shfl_xor(part, 1);
      part += __shfl_xor(part, 2);
      part += __shfl_xor(part, 4);
      part += __shfl_xor(part, 8);
      if (l15 == 0)
        sL[(wv << 5) + (mt << 4) + (lq << 2) + rr] = part;
    }
  }
  __syncthreads();

  // ---- final: sij = sm_i + sm_j + s + b3, masked; epsilon col = 0 ----
  if (tid < 128) {
    const int rg = mbase + tid;
    if (rg <= WINW) {
      const int j = i - WINW + rg;
      float v = 0.f;
      if (rg < WINW && j >= 0)
        v = sL[tid] + b3[0] + sm[i] + sm[j];
      out[(size_t)i * OUTW + rg] = v;
    }
  }
}

extern "C" void kernel_launch(void* const* d_in, const int* in_sizes, int n_in,
                              void* d_out, int out_size, void* d_ws, size_t ws_size,
                              hipStream_t stream) {
  const float* g  = (const float*)d_in[0];
  const float* sm = (const float*)d_in[1];
  const float* W1 = (const float*)d_in[2];
  const float* b1 = (const float*)d_in[3];
  const float* W2 = (const float*)d_in[4];
  const float* b2 = (const float*)d_in[5];
  const float* W3 = (const float*)d_in[6];
  const float* b3 = (const float*)d_in[7];
  float* out = (float*)d_out;

  // workspace carve (total 1,526,400 B)
  char* ws = (char*)d_ws;
  float* pre1          = (float*)ws;                         // 1024*160*4 = 655360
  float* gjb           = (float*)(ws + 655360);              // 655360
  unsigned short* w1cT = (unsigned short*)(ws + 1310720);    // 160*512*2 = 163840
  unsigned short* w2T  = (unsigned short*)(ws + 1474560);    // 160*160*2 = 51200
  float* w3p           = (float*)(ws + 1525760);             // 640

  // merged prep: blocks [0,1024) gemm part, [1024,1585) misc part
  prep_all<<<1585, 192, 0, stream>>>(g, W1, b1, W2, W3, pre1, gjb, w1cT, w2T, w3p);
  pair_main<<<2048, 256, 0, stream>>>(g, sm, pre1, gjb, w1cT, w2T, w3p, b2, b3, out);
}

// Round 8
// 206.867 us; speedup vs baseline: 1.7126x; 1.2276x over previous
//
#include <hip/hip_runtime.h>

typedef __attribute__((ext_vector_type(8))) short short8;
typedef __attribute__((ext_vector_type(4))) float f32x4;

// ---- problem constants ----
#define NSPAN 1024
#define DDIM  512
#define HDIM  150
#define HPAD  160
#define WINW  250
#define OUTW  251

// ---- LDS layout (pair_main), 40960 B total -> 4 blocks/CU ----
// GEMM1: B dbuf @0 / @10240 (160 rows x 64B each)
// GEMM2: A2 (h1 bf16 [128] rows x 320B, wave-private rows) @0 (aliases B bufs)
// GEMM3: sL (f32[128]) @0 (aliases A2 rows 0-1; barrier-separated)
#define SMEM_BYTES 40960

__device__ __forceinline__ unsigned short f2bf(float x) {
  union { float f; unsigned int u; } v; v.f = x;
  return (unsigned short)((v.u + 0x7fffu + ((v.u >> 16) & 1u)) >> 16);
}

// v_cvt_pk_bf16_f32: dst = {lo16=bf16(a), hi16=bf16(b)}, RNE
__device__ __forceinline__ unsigned int cvtpk(float a, float b) {
  unsigned int r;
  asm("v_cvt_pk_bf16_f32 %0, %1, %2" : "=v"(r) : "v"(a), "v"(b));
  return r;
}

__device__ __forceinline__ void gload_lds16(const void* g, void* l) {
  __builtin_amdgcn_global_load_lds(
      (const __attribute__((address_space(1))) unsigned int*)g,
      (__attribute__((address_space(3))) unsigned int*)l, 16, 0, 0);
}

// ---------------- merged prep (one launch; gemm part + misc part overlap) ----------------
__global__ __launch_bounds__(192) void prep_all(
    const float* __restrict__ g, const float* __restrict__ W1,
    const float* __restrict__ b1, const float* __restrict__ W2,
    const float* __restrict__ W3,
    float* __restrict__ pre1, float* __restrict__ gjb,
    unsigned short* __restrict__ w1cT, unsigned short* __restrict__ w2T,
    float* __restrict__ w3p)
{
  const int bx = blockIdx.x;
  if (bx < 1024) {
    __shared__ __align__(16) float gs[2 * DDIM];
    const int grp = bx >> 1;
    const int which = bx & 1;
    const int i0 = grp << 1;
    for (int idx = threadIdx.x; idx < (2 * DDIM / 4); idx += 192)
      ((float4*)gs)[idx] = ((const float4*)(g + (size_t)i0 * DDIM))[idx];
    __syncthreads();
    const int n = threadIdx.x;
    float a0 = 0.f, a1 = 0.f;
    if (n < HDIM) {
      const float* Wp = W1 + (size_t)which * DDIM * HDIM + n;
#pragma unroll 8
      for (int d = 0; d < DDIM; ++d) {
        float w = Wp[(size_t)d * HDIM];
        a0 += gs[d] * w;
        a1 += gs[DDIM + d] * w;
      }
    }
    if (n < HPAD) {
      float* dst = which ? gjb : pre1;
      float add = (which == 0 && n < HDIM) ? b1[n] : 0.f;
      dst[(size_t)i0 * HPAD + n]       = (n < HDIM) ? (a0 + add) : 0.f;
      dst[(size_t)(i0 + 1) * HPAD + n] = (n < HDIM) ? (a1 + add) : 0.f;
    }
  } else {
    int id = (bx - 1024) * 192 + threadIdx.x;
    if (id < HPAD * DDIM) {                       // 81920: id = d*160 + n
      int d = id / HPAD, n = id % HPAD;
      float v = (n < HDIM) ? W1[(size_t)(2 * DDIM + d) * HDIM + n] : 0.f;
      w1cT[(size_t)n * DDIM + d] = f2bf(v);
    } else if (id < HPAD * DDIM + HPAD * HPAD) {  // +25600: id2 = k*160 + n
      int id2 = id - HPAD * DDIM;
      int k = id2 / HPAD, n = id2 % HPAD;
      float v = (n < HDIM && k < HDIM) ? W2[(size_t)k * HDIM + n] : 0.f;
      w2T[(size_t)n * HPAD + k] = f2bf(v);
    } else if (id < HPAD * DDIM + HPAD * HPAD + HPAD) {
      int n = id - HPAD * DDIM - HPAD * HPAD;
      w3p[n] = (n < HDIM) ? W3[n] : 0.f;
    }
  }
}

// ---------------- main fused kernel ----------------
// block = (i, half): 128 window rows. 4 waves, each owns rows [wv*32, wv*32+32).
// R4-proven GEMM1 sync (stage -> pack -> barrier -> MFMA) with A built in regs.
// Register diet (xb via ds_read imm offsets; A-in-regs; sL alias) targets 128
// regs -> 4 waves/SIMD (16 waves/CU).
__global__ __launch_bounds__(256, 4) void pair_main(
    const float* __restrict__ g, const float* __restrict__ sm,
    const float* __restrict__ pre1, const float* __restrict__ gjb,
    const unsigned short* __restrict__ w1cT, const unsigned short* __restrict__ w2T,
    const float* __restrict__ w3p, const float* __restrict__ b2,
    const float* __restrict__ b3, float* __restrict__ out)
{
  __shared__ __align__(16) char smem[SMEM_BYTES];
  const int tid = threadIdx.x;
  const int lane = tid & 63;
  const int wv = tid >> 6;
  const int l15 = lane & 15;
  const int lq = lane >> 4;          // 0..3
  const int i = blockIdx.x >> 1;
  const int mbase = (blockIdx.x & 1) << 7;

  // per-lane A row pointers (mt = 0,1): row = mbase + wv*32 + mt*16 + l15
  const int row0 = mbase + (wv << 5) + l15;
  int j0 = i - WINW + row0;
  j0 = j0 < 0 ? 0 : (j0 > NSPAN - 1 ? NSPAN - 1 : j0);
  int j1 = i - WINW + row0 + 16;
  j1 = j1 < 0 ? 0 : (j1 > NSPAN - 1 ? NSPAN - 1 : j1);
  const float* gjr0 = g + (size_t)j0 * DDIM + (lq << 3);
  const float* gjr1 = g + (size_t)j1 * DDIM + (lq << 3);
  const float* giR  = g + (size_t)i * DDIM + (lq << 3);

  // B global_load_lds: per-lane inverse-swizzled source byte offsets (k0=0)
  unsigned int bsrc[3];
#pragma unroll
  for (int t = 0; t < 3; ++t) {
    int b = wv * 2560 + (t << 10) + (lane << 4);
    int m = b >> 7;                       // 128B row-pair block
    int bp = b ^ ((m & 7) << 4);          // involution within block
    int n = bp >> 6, o = bp & 63;
    bsrc[t] = (unsigned int)(n * 1024 + o);   // + s*64 at use (w1cT row = 1024B)
  }

  // B fragment read base: xb[nt] = xb0 + nt*1024 (the XOR term ((nr>>1)&7) is
  // nt-independent: (nt<<3)&7 == 0), so all reads use one vaddr + imm offset.
  const int xb0 = ((l15 << 6) + (lq << 4)) ^ ((l15 >> 1) << 4);

  f32x4 acc[2][10];
#pragma unroll
  for (int mt = 0; mt < 2; ++mt)
#pragma unroll
    for (int nt = 0; nt < 10; ++nt)
      acc[mt][nt] = (f32x4){0.f, 0.f, 0.f, 0.f};

  const char* w1cB = (const char*)w1cT;

  // ---- GEMM1: [128 x 512] (g_i*g_j bf16, regs) @ [512 x 160] (W1c via LDS dbuf) ----
  // per step: A-loads, stage B(s), pack A (waits A; DMA keeps flying), barrier
  // (drains DMA with pack as cover), 20 MFMAs. R4-proven placement.
#pragma unroll 2
  for (int s = 0; s < 16; ++s) {
    const int kf = s << 5;
    float4 x0 = *(const float4*)(gjr0 + kf), x1 = *(const float4*)(gjr0 + kf + 4);
    float4 y0 = *(const float4*)(gjr1 + kf), y1 = *(const float4*)(gjr1 + kf + 4);
    float4 g0 = *(const float4*)(giR + kf),  g1 = *(const float4*)(giR + kf + 4);
    {
      char* ldsw = smem + (s & 1) * 10240 + wv * 2560;
      const int kn = s << 6;
      gload_lds16(w1cB + bsrc[0] + kn, ldsw);
      gload_lds16(w1cB + bsrc[1] + kn, ldsw + 1024);
      if (lane < 32) gload_lds16(w1cB + bsrc[2] + kn, ldsw + 2048);
    }
    uint4 aC0, aC1;
    aC0.x = cvtpk(x0.x * g0.x, x0.y * g0.y);
    aC0.y = cvtpk(x0.z * g0.z, x0.w * g0.w);
    aC0.z = cvtpk(x1.x * g1.x, x1.y * g1.y);
    aC0.w = cvtpk(x1.z * g1.z, x1.w * g1.w);
    aC1.x = cvtpk(y0.x * g0.x, y0.y * g0.y);
    aC1.y = cvtpk(y0.z * g0.z, y0.w * g0.w);
    aC1.z = cvtpk(y1.x * g1.x, y1.y * g1.y);
    aC1.w = cvtpk(y1.z * g1.z, y1.w * g1.w);
    __syncthreads();   // B(s) visible to all waves; dbuf WAR-safe

    const char* bcur = smem + (s & 1) * 10240 + xb0;
    short8 a0 = *(short8*)&aC0;
    short8 a1 = *(short8*)&aC1;
    __builtin_amdgcn_s_setprio(1);
#pragma unroll
    for (int nt = 0; nt < 10; ++nt) {
      short8 bb = *(const short8*)(bcur + (nt << 10));
      acc[0][nt] = __builtin_amdgcn_mfma_f32_16x16x32_bf16(a0, bb, acc[0][nt], 0, 0, 0);
      acc[1][nt] = __builtin_amdgcn_mfma_f32_16x16x32_bf16(a1, bb, acc[1][nt], 0, 0, 0);
    }
    __builtin_amdgcn_s_setprio(0);
  }
  __syncthreads();   // all waves done reading B dbuf before A2 overwrites it

  // ---- epilogue 1: h1 = relu(acc + pre1_i + gjb_j) -> A2 @0 (bf16, swizzled) ----
  // A2 rows are wave-private -> no barrier needed before GEMM2.
  float p1v[10];
#pragma unroll
  for (int nt = 0; nt < 10; ++nt)
    p1v[nt] = pre1[(size_t)i * HPAD + (nt << 4) + l15];

#pragma unroll
  for (int mt = 0; mt < 2; ++mt) {
#pragma unroll
    for (int rr = 0; rr < 4; ++rr) {
      const int row = (wv << 5) + (mt << 4) + (lq << 2) + rr;
      int j = i - WINW + mbase + row;
      j = j < 0 ? 0 : (j > NSPAN - 1 ? NSPAN - 1 : j);
      const float* gjr = gjb + (size_t)j * HPAD;
      const int sw = ((row + (row >> 2)) & 3) << 4;
      const int rb = row * 320;
#pragma unroll
      for (int np = 0; np < 5; ++np) {
        const int n0 = np << 1, n1 = n0 + 1;
        float v0 = fmaxf(acc[mt][n0][rr] + p1v[n0] + gjr[(n0 << 4) + l15], 0.f);
        float v1 = fmaxf(acc[mt][n1][rr] + p1v[n1] + gjr[(n1 << 4) + l15], 0.f);
        unsigned int u = cvtpk(v0, v1);
        *(unsigned short*)(smem + ((rb + (((n0 << 4) + l15) << 1)) ^ sw)) = (unsigned short)u;
        *(unsigned short*)(smem + ((rb + (((n1 << 4) + l15) << 1)) ^ sw)) = (unsigned short)(u >> 16);
      }
    }
  }

  // ---- GEMM2: [128 x 160] (h1 from LDS, own rows) @ [160 x 160] (W2 from L2) ----
  int ya[2];
#pragma unroll
  for (int mt = 0; mt < 2; ++mt) {
    int row = (wv << 5) + (mt << 4) + l15;
    ya[mt] = ((row * 320) + (lq << 4)) ^ (((row + (row >> 2)) & 3) << 4);
  }

#pragma unroll
  for (int mt = 0; mt < 2; ++mt)
#pragma unroll
    for (int nt = 0; nt < 10; ++nt)
      acc[mt][nt] = (f32x4){0.f, 0.f, 0.f, 0.f};

#pragma unroll
  for (int c = 0; c < 5; ++c) {
    short8 a0 = *(const short8*)(smem + ya[0] + (c << 6));
    short8 a1 = *(const short8*)(smem + ya[1] + (c << 6));
    __builtin_amdgcn_s_setprio(1);
#pragma unroll
    for (int nt = 0; nt < 10; ++nt) {
      short8 bb = *(const short8*)(w2T + (size_t)((nt << 4) + l15) * HPAD + (c << 5) + (lq << 3));
      acc[0][nt] = __builtin_amdgcn_mfma_f32_16x16x32_bf16(a0, bb, acc[0][nt], 0, 0, 0);
      acc[1][nt] = __builtin_amdgcn_mfma_f32_16x16x32_bf16(a1, bb, acc[1][nt], 0, 0, 0);
    }
    __builtin_amdgcn_s_setprio(0);
  }
  __syncthreads();   // all A2 reads done before sL (@0) overwrites A2 rows 0-1

  // ---- GEMM3: s = relu(acc + b2) @ W3, 16-lane shuffle reduce ----
  float w3v[10], b2v[10];
#pragma unroll
  for (int nt = 0; nt < 10; ++nt) {
    int nn = (nt << 4) + l15;
    w3v[nt] = w3p[nn];
    b2v[nt] = (nn < HDIM) ? b2[nn] : 0.f;
  }
  float* sL = (float*)smem;
#pragma unroll
  for (int mt = 0; mt < 2; ++mt) {
#pragma unroll
    for (int rr = 0; rr < 4; ++rr) {
      float part = 0.f;
#pragma unroll
      for (int nt = 0; nt < 10; ++nt) {
        float h2 = fmaxf(acc[mt][nt][rr] + b2v[nt], 0.f);
        part = fmaf(h2, w3v[nt], part);
      }
      part += __shfl_xor(part, 1);
      part += __shfl_xor(part, 2);
      part += __shfl_xor(part, 4);
      part += __shfl_xor(part, 8);
      if (l15 == 0)
        sL[(wv << 5) + (mt << 4) + (lq << 2) + rr] = part;
    }
  }
  __syncthreads();

  // ---- final: sij = sm_i + sm_j + s + b3, masked; epsilon col = 0 ----
  if (tid < 128) {
    const int rg = mbase + tid;
    if (rg <= WINW) {
      const int j = i - WINW + rg;
      float v = 0.f;
      if (rg < WINW && j >= 0)
        v = sL[tid] + b3[0] + sm[i] + sm[j];
      out[(size_t)i * OUTW + rg] = v;
    }
  }
}

extern "C" void kernel_launch(void* const* d_in, const int* in_sizes, int n_in,
                              void* d_out, int out_size, void* d_ws, size_t ws_size,
                              hipStream_t stream) {
  const float* g  = (const float*)d_in[0];
  const float* sm = (const float*)d_in[1];
  const float* W1 = (const float*)d_in[2];
  const float* b1 = (const float*)d_in[3];
  const float* W2 = (const float*)d_in[4];
  const float* b2 = (const float*)d_in[5];
  const float* W3 = (const float*)d_in[6];
  const float* b3 = (const float*)d_in[7];
  float* out = (float*)d_out;

  // workspace carve (total 1,526,400 B)
  char* ws = (char*)d_ws;
  float* pre1          = (float*)ws;                         // 1024*160*4 = 655360
  float* gjb           = (float*)(ws + 655360);              // 655360
  unsigned short* w1cT = (unsigned short*)(ws + 1310720);    // 160*512*2 = 163840
  unsigned short* w2T  = (unsigned short*)(ws + 1474560);    // 160*160*2 = 51200
  float* w3p           = (float*)(ws + 1525760);             // 640

  // merged prep: blocks [0,1024) gemm part, [1024,1585) misc part
  prep_all<<<1585, 192, 0, stream>>>(g, W1, b1, W2, W3, pre1, gjb, w1cT, w2T, w3p);
  pair_main<<<2048, 256, 0, stream>>>(g, sm, pre1, gjb, w1cT, w2T, w3p, b2, b3, out);
}